// Round 5
// baseline (64623.944 us; speedup 1.0000x reference)
//
#include <hip/hip_runtime.h>
#include <hip/hip_bf16.h>
#include <math.h>

#define B_ 64
#define T_ 512
#define I_ 512
#define H_ 1024

// ---------------------------------------------------------------------------
// C[M,N] = A[M,K] @ Bt[N,K]^T + bias1[n] (+ bias2[n])
// A row r (r = t_local*64 + b) is at A + (r&63)*s1 + (r>>6)*s2.
// Tile 128x128, BK=8, 256 threads, 8x8 per-thread register block. (validated)
// ---------------------------------------------------------------------------
__global__ __launch_bounds__(256) void gemm_bt_bias(
    const float* __restrict__ A, const float* __restrict__ Bt,
    const float* __restrict__ bias1, const float* __restrict__ bias2,
    float* __restrict__ C, int N, int K, long s1, long s2)
{
  __shared__ float As[8][132];   // 132%32==4 -> per-row bank rotation
  __shared__ float Bs[8][132];
  const int t   = threadIdx.x;
  const int r0  = blockIdx.y * 128;
  const int n0  = blockIdx.x * 128;
  const int lm  = t >> 1;
  const int lk4 = (t & 1) * 4;
  const int tm0 = (t >> 4) * 8;
  const int tn0 = (t & 15) * 8;

  float acc[8][8] = {};

  for (int k0 = 0; k0 < K; k0 += 8) {
    const int r = r0 + lm;
    const float4 a = *(const float4*)(A + (long)(r & 63) * s1 + (long)(r >> 6) * s2 + k0 + lk4);
    const float4 b = *(const float4*)(Bt + (long)(n0 + lm) * K + k0 + lk4);
    As[lk4 + 0][lm] = a.x; As[lk4 + 1][lm] = a.y; As[lk4 + 2][lm] = a.z; As[lk4 + 3][lm] = a.w;
    Bs[lk4 + 0][lm] = b.x; Bs[lk4 + 1][lm] = b.y; Bs[lk4 + 2][lm] = b.z; Bs[lk4 + 3][lm] = b.w;
    __syncthreads();
#pragma unroll
    for (int kk = 0; kk < 8; ++kk) {
      const float4 a0 = *(const float4*)&As[kk][tm0];
      const float4 a1 = *(const float4*)&As[kk][tm0 + 4];
      const float4 b0 = *(const float4*)&Bs[kk][tn0];
      const float4 b1 = *(const float4*)&Bs[kk][tn0 + 4];
      const float am[8] = {a0.x, a0.y, a0.z, a0.w, a1.x, a1.y, a1.z, a1.w};
      const float bn[8] = {b0.x, b0.y, b0.z, b0.w, b1.x, b1.y, b1.z, b1.w};
#pragma unroll
      for (int i = 0; i < 8; ++i)
#pragma unroll
        for (int j = 0; j < 8; ++j)
          acc[i][j] = fmaf(am[i], bn[j], acc[i][j]);
    }
    __syncthreads();
  }

  float bs[8];
#pragma unroll
  for (int j = 0; j < 8; ++j) {
    const int n = n0 + tn0 + j;
    bs[j] = bias1[n] + (bias2 ? bias2[n] : 0.f);
  }
#pragma unroll
  for (int i = 0; i < 8; ++i) {
    const long r = r0 + tm0 + i;
    const float4 v0 = make_float4(acc[i][0] + bs[0], acc[i][1] + bs[1],
                                  acc[i][2] + bs[2], acc[i][3] + bs[3]);
    const float4 v1 = make_float4(acc[i][4] + bs[4], acc[i][5] + bs[5],
                                  acc[i][6] + bs[6], acc[i][7] + bs[7]);
    *(float4*)(C + r * N + n0 + tn0)     = v0;
    *(float4*)(C + r * N + n0 + tn0 + 4) = v1;
  }
}

// ---------------------------------------------------------------------------
// Distributed grid barrier (contention-free arrive):
//  - WG i (i>0): release-store target into its OWN 128B flag slot, then poll
//    the single release word (read-only sharing).
//  - WG 0: 256 threads poll the 255 flag slots in parallel, then thread 0
//    release-stores the release word.
// Monotonic targets; flags zeroed each kernel_launch by memset. All-WG
// co-residency guaranteed by hipLaunchCooperativeKernel.
// Replaces the single-counter barrier measured at ~30us/step (256 contended
// device-scope RMWs on one line). Predicted ~3-5us.
// ---------------------------------------------------------------------------
__device__ __forceinline__ void grid_barrier(unsigned* flags, unsigned* rel,
                                             int wg, unsigned target)
{
  __threadfence();   // publish this thread's h/hL stores (agent scope)
  __syncthreads();   // whole WG's stores are issued+fenced
  const int tid = threadIdx.x;
  if (wg == 0) {
    if (tid >= 1) {
      while (__hip_atomic_load(flags + tid * 32, __ATOMIC_ACQUIRE,
                               __HIP_MEMORY_SCOPE_AGENT) < target)
        __builtin_amdgcn_s_sleep(1);
    }
    __syncthreads();
    if (tid == 0)
      __hip_atomic_store(rel, target, __ATOMIC_RELEASE, __HIP_MEMORY_SCOPE_AGENT);
  } else {
    if (tid == 0) {
      __hip_atomic_store(flags + wg * 32, target, __ATOMIC_RELEASE,
                         __HIP_MEMORY_SCOPE_AGENT);
      while (__hip_atomic_load(rel, __ATOMIC_ACQUIRE,
                               __HIP_MEMORY_SCOPE_AGENT) < target)
        __builtin_amdgcn_s_sleep(1);
    }
    __syncthreads();
  }
  __threadfence();   // acquire side: L1 invalidate before reading others' data
}

// lane-select without runtime array indexing (keeps values in VGPRs)
__device__ __forceinline__ float sel4(float a, float b, float c, float d, int u)
{
  return (u & 2) ? ((u & 1) ? d : c) : ((u & 1) ? b : a);
}

// ---------------------------------------------------------------------------
// FUSED persistent scan (cooperative): LSTM + fc_in + liquid in ONE kernel,
// ONE barrier per step. Phase at global step s computes:
//   - LSTM h_s from h_{s-1} (W_hh dots, k-split by lane u over quarters)
//   - liquid state_{s-1} from state_{s-2} and xi_{s-1} = h_{s-1}@W_in^T + b_in
//     (liquid lags one step; both phases read only data published at the
//      end-of-step-(s-1) barrier -> single barrier suffices)
// The h_{s-1} quarter load is SHARED by the W_hh and W_in dots.
// Epilogue (last chunk): liquid state_{T-1} -> out.
// WG j owns units j*4..j*4+3. LDS: W_hh 16 rows + W_in 4 + W_rec 4, quarter-
// padded (stride 260 -> bases hit banks {0,4,8,12}; 16-lane broadcast) ~97.5KB.
// c in register (cbuf across chunks); h, hL double-buffered in global,
// parity by global step index (chunks even -> invariant holds).
// ---------------------------------------------------------------------------
__global__ __launch_bounds__(256) void fused_scan(
    const float* __restrict__ W_hh, const float* __restrict__ W_in,
    const float* __restrict__ W_rec, const float* __restrict__ gx,
    const float* __restrict__ b_in, const float* __restrict__ b_rec,
    const float* __restrict__ tau,
    float* __restrict__ hA, float* __restrict__ hB,
    float* __restrict__ hLA, float* __restrict__ hLB,
    float* __restrict__ cbuf, float* __restrict__ out,
    unsigned* __restrict__ flags, unsigned* __restrict__ rel,
    int base, int nsteps, int do_epi)
{
  __shared__ float Whh[16][1040];  // row r = gate*4+unit; quarter q at q*260
  __shared__ float Win[4][1040];
  __shared__ float Wrc[4][1040];
  const int wg = blockIdx.x, t = threadIdx.x;
  {
    const int ru = t >> 4, l16 = t & 15;
    const int q = ru >> 2, uu = ru & 3;
    const float* src = W_hh + (long)(q * H_ + wg * 4 + uu) * H_;
#pragma unroll
    for (int j = 0; j < 16; ++j) {
      const int k = l16 * 4 + j * 64;
      *(float4*)&Whh[ru][(k >> 8) * 260 + (k & 255)] = *(const float4*)(src + k);
    }
  }
  {
    const int ru = t >> 6, c0 = (t & 63) * 4;
    const float* si = W_in  + (long)(wg * 4 + ru) * H_;
    const float* sr = W_rec + (long)(wg * 4 + ru) * H_;
#pragma unroll
    for (int j = 0; j < 4; ++j) {
      Win[ru][j * 260 + c0 + 0] = 0.f;  // placeholder to keep layout symmetric
      *(float4*)&Win[ru][j * 260 + c0] = *(const float4*)(si + c0 + j * 256);
      *(float4*)&Wrc[ru][j * 260 + c0] = *(const float4*)(sr + c0 + j * 256);
    }
  }
  __syncthreads();

  const int b = t >> 2, u = t & 3;
  const int unit = wg * 4 + u;
  float creg = cbuf[b * H_ + unit];
  const float tc   = fminf(fmaxf(tau[unit], 0.1f), 5.0f);
  const float leak = 0.1f / tc;   // DT / clip(tau)
  const float br   = b_rec[unit];
  const float bi   = b_in[unit];

  const float* wq  = &Whh[0][0] + u * 260;   // this lane's W_hh quarter base
  const float* wiq = &Win[0][0] + u * 260;
  const float* wrq = &Wrc[0][0] + u * 260;

  for (int ls = 0; ls < nsteps; ++ls) {
    const int s = base + ls;                  // global LSTM step
    const int j = s - 1;                      // global liquid step (lags 1)
    const float* hp  = (s & 1) ? hB : hA;     // h_{s-1}
    float*       hn  = (s & 1) ? hA : hB;     // h_s
    const float* hLp = (j & 1) ? hLB : hLA;   // liquid state_{j-1}
    float*       hLn = (j & 1) ? hLA : hLB;   // liquid state_j
    const float* hq  = hp  + b * H_ + u * 256;
    const float* hLq = hLp + b * H_ + u * 256;

    float p[4][4] = {};                 // W_hh partials [gate][unit-in-group]
    float qi[4] = {};                   // W_in partials
    float rr[4] = {};                   // W_rec partials
#pragma unroll 2
    for (int k4 = 0; k4 < 64; ++k4) {
      const float4 hv  = *(const float4*)(hq  + k4 * 4);
      const float4 hlv = *(const float4*)(hLq + k4 * 4);
#pragma unroll
      for (int r = 0; r < 16; ++r) {
        const float4 wv = *(const float4*)(wq + r * 1040 + k4 * 4);
        float& a = p[r >> 2][r & 3];
        a = fmaf(hv.x, wv.x, a); a = fmaf(hv.y, wv.y, a);
        a = fmaf(hv.z, wv.z, a); a = fmaf(hv.w, wv.w, a);
      }
#pragma unroll
      for (int r = 0; r < 4; ++r) {
        const float4 wv = *(const float4*)(wiq + r * 1040 + k4 * 4);
        float& a = qi[r];
        a = fmaf(hv.x, wv.x, a); a = fmaf(hv.y, wv.y, a);
        a = fmaf(hv.z, wv.z, a); a = fmaf(hv.w, wv.w, a);
      }
#pragma unroll
      for (int r = 0; r < 4; ++r) {
        const float4 wv = *(const float4*)(wrq + r * 1040 + k4 * 4);
        float& a = rr[r];
        a = fmaf(hlv.x, wv.x, a); a = fmaf(hlv.y, wv.y, a);
        a = fmaf(hlv.z, wv.z, a); a = fmaf(hlv.w, wv.w, a);
      }
    }
    // combine the 4 k-quarters (lanes 4b..4b+3)
#pragma unroll
    for (int g = 0; g < 4; ++g)
#pragma unroll
      for (int uu = 0; uu < 4; ++uu) {
        p[g][uu] += __shfl_xor(p[g][uu], 1, 64);
        p[g][uu] += __shfl_xor(p[g][uu], 2, 64);
      }
#pragma unroll
    for (int r = 0; r < 4; ++r) {
      qi[r] += __shfl_xor(qi[r], 1, 64); qi[r] += __shfl_xor(qi[r], 2, 64);
      rr[r] += __shfl_xor(rr[r], 1, 64); rr[r] += __shfl_xor(rr[r], 2, 64);
    }

    // ---- LSTM update for (b, unit) ----
    const float* gp = gx + (long)ls * (B_ * 4 * H_) + b * (4 * H_);
    const float gi = sel4(p[0][0], p[0][1], p[0][2], p[0][3], u) + gp[unit];
    const float gf = sel4(p[1][0], p[1][1], p[1][2], p[1][3], u) + gp[H_ + unit];
    const float gg = sel4(p[2][0], p[2][1], p[2][2], p[2][3], u) + gp[2 * H_ + unit];
    const float go = sel4(p[3][0], p[3][1], p[3][2], p[3][3], u) + gp[3 * H_ + unit];
    const float si = 1.f / (1.f + __expf(-gi));
    const float sf = 1.f / (1.f + __expf(-gf));
    const float so = 1.f / (1.f + __expf(-go));
    const float tg = tanhf(gg);
    creg = sf * creg + si * tg;
    hn[b * H_ + unit] = so * tanhf(creg);

    // ---- liquid update for step j = s-1 (skip before first step) ----
    if (s > 0) {
      const float xi    = sel4(qi[0], qi[1], qi[2], qi[3], u) + bi;
      const float rec   = sel4(rr[0], rr[1], rr[2], rr[3], u);
      const float hself = hLp[b * H_ + unit];
      const float act   = tanhf(xi + rec + br);
      hLn[b * H_ + unit] = hself + leak * (act - hself);
    }

    grid_barrier(flags, rel, wg, (unsigned)(s + 1));
  }
  cbuf[b * H_ + unit] = creg;

  // ---- epilogue (last chunk): liquid step T-1 -> out ----
  if (do_epi) {
    const int j = base + nsteps - 1;          // = T_-1
    const float* hp  = (j & 1) ? hA : hB;     // h_j (written at phase s=j)
    const float* hLp = (j & 1) ? hLB : hLA;   // state_{j-1}
    const float* hq  = hp  + b * H_ + u * 256;
    const float* hLq = hLp + b * H_ + u * 256;
    float qi[4] = {}, rr[4] = {};
#pragma unroll 4
    for (int k4 = 0; k4 < 64; ++k4) {
      const float4 hv  = *(const float4*)(hq  + k4 * 4);
      const float4 hlv = *(const float4*)(hLq + k4 * 4);
#pragma unroll
      for (int r = 0; r < 4; ++r) {
        const float4 wv = *(const float4*)(wiq + r * 1040 + k4 * 4);
        const float4 wr = *(const float4*)(wrq + r * 1040 + k4 * 4);
        float& a = qi[r];
        a = fmaf(hv.x, wv.x, a); a = fmaf(hv.y, wv.y, a);
        a = fmaf(hv.z, wv.z, a); a = fmaf(hv.w, wv.w, a);
        float& c = rr[r];
        c = fmaf(hlv.x, wr.x, c); c = fmaf(hlv.y, wr.y, c);
        c = fmaf(hlv.z, wr.z, c); c = fmaf(hlv.w, wr.w, c);
      }
    }
#pragma unroll
    for (int r = 0; r < 4; ++r) {
      qi[r] += __shfl_xor(qi[r], 1, 64); qi[r] += __shfl_xor(qi[r], 2, 64);
      rr[r] += __shfl_xor(rr[r], 1, 64); rr[r] += __shfl_xor(rr[r], 2, 64);
    }
    const float xi    = sel4(qi[0], qi[1], qi[2], qi[3], u) + bi;
    const float rec   = sel4(rr[0], rr[1], rr[2], rr[3], u);
    const float hself = hLp[b * H_ + unit];
    const float act   = tanhf(xi + rec + br);
    out[b * H_ + unit] = hself + leak * (act - hself);
  }
}

// ---------------------------------------------------------------------------
extern "C" void kernel_launch(void* const* d_in, const int* in_sizes, int n_in,
                              void* d_out, int out_size, void* d_ws, size_t ws_size,
                              hipStream_t stream)
{
  (void)in_sizes; (void)n_in; (void)out_size;
  const float* x     = (const float*)d_in[0];
  const float* W_ih  = (const float*)d_in[1];
  const float* W_hh  = (const float*)d_in[2];
  const float* b_ih  = (const float*)d_in[3];
  const float* b_hh  = (const float*)d_in[4];
  const float* W_in  = (const float*)d_in[5];
  const float* b_in  = (const float*)d_in[6];
  const float* W_rec = (const float*)d_in[7];
  const float* b_rec = (const float*)d_in[8];
  const float* tau   = (const float*)d_in[9];

  const size_t HB   = (size_t)B_ * H_ * sizeof(float);        // 256 KiB
  const size_t FLB  = 256 * 128 + 256;                        // flags + release
  const size_t TAIL = 5 * HB + FLB;   // cbuf, hA, hB, hLA, hLB, flags

  // Largest chunk length (even, divides T_) whose gx buffer fits. (no ys!)
  int Tc = T_;
  while (Tc > 2) {
    const size_t need = (size_t)Tc * B_ * 4 * H_ * 4 + TAIL;
    if (need <= ws_size) break;
    Tc >>= 1;
  }

  char* ws = (char*)d_ws;
  const size_t GXB = (size_t)Tc * B_ * 4 * H_ * sizeof(float);
  float* gx   = (float*)ws;                    // [Tc][B][4H]
  char*  tail = ws + GXB;
  float* cbuf = (float*)(tail);
  float* hA   = (float*)(tail + 1 * HB);
  float* hB   = (float*)(tail + 2 * HB);
  float* hLA  = (float*)(tail + 3 * HB);
  float* hLB  = (float*)(tail + 4 * HB);
  unsigned* flags = (unsigned*)(tail + 5 * HB);          // 256 x 128B slots
  unsigned* rel   = (unsigned*)(tail + 5 * HB + 256 * 128);
  float* outp = (float*)d_out;

  // zero c/h/hL state + flags (ws is re-poisoned to 0xAA before every launch)
  hipMemsetAsync(tail, 0, TAIL, stream);

  const int nch = T_ / Tc;
  for (int k = 0; k < nch; ++k) {
    int t0 = k * Tc;
    int ns = Tc;
    int epi = (k == nch - 1) ? 1 : 0;

    // K1: gx[t][b][g] = x[b][t0+t][:] @ W_ih^T + b_ih + b_hh
    gemm_bt_bias<<<dim3(4 * H_ / 128, Tc * B_ / 128), 256, 0, stream>>>(
        x + (long)t0 * I_, W_ih, b_ih, b_hh, gx, 4 * H_, I_,
        (long)T_ * I_, (long)I_);

    // K2: fused LSTM + liquid persistent scan over this chunk
    {
      void* args[] = {(void*)&W_hh, (void*)&W_in, (void*)&W_rec, (void*)&gx,
                      (void*)&b_in, (void*)&b_rec, (void*)&tau,
                      (void*)&hA, (void*)&hB, (void*)&hLA, (void*)&hLB,
                      (void*)&cbuf, (void*)&outp, (void*)&flags, (void*)&rel,
                      (void*)&t0, (void*)&ns, (void*)&epi};
      hipLaunchCooperativeKernel((void*)fused_scan, dim3(256), dim3(256),
                                 args, 0, stream);
    }
  }
}

// Round 8
// 34165.451 us; speedup vs baseline: 1.8915x; 1.8915x over previous
//
#include <hip/hip_runtime.h>
#include <hip/hip_bf16.h>
#include <math.h>

#define B_ 64
#define T_ 512
#define I_ 512
#define H_ 1024

// ---------------------------------------------------------------------------
// C[M,N] = A[M,K] @ Bt[N,K]^T + bias1 (+ bias2). Validated rounds 4/5.
// ---------------------------------------------------------------------------
__global__ __launch_bounds__(256) void gemm_bt_bias(
    const float* __restrict__ A, const float* __restrict__ Bt,
    const float* __restrict__ bias1, const float* __restrict__ bias2,
    float* __restrict__ C, int N, int K, long s1, long s2)
{
  __shared__ float As[8][132];
  __shared__ float Bs[8][132];
  const int t   = threadIdx.x;
  const int r0  = blockIdx.y * 128;
  const int n0  = blockIdx.x * 128;
  const int lm  = t >> 1;
  const int lk4 = (t & 1) * 4;
  const int tm0 = (t >> 4) * 8;
  const int tn0 = (t & 15) * 8;

  float acc[8][8] = {};

  for (int k0 = 0; k0 < K; k0 += 8) {
    const int r = r0 + lm;
    const float4 a = *(const float4*)(A + (long)(r & 63) * s1 + (long)(r >> 6) * s2 + k0 + lk4);
    const float4 b = *(const float4*)(Bt + (long)(n0 + lm) * K + k0 + lk4);
    As[lk4 + 0][lm] = a.x; As[lk4 + 1][lm] = a.y; As[lk4 + 2][lm] = a.z; As[lk4 + 3][lm] = a.w;
    Bs[lk4 + 0][lm] = b.x; Bs[lk4 + 1][lm] = b.y; Bs[lk4 + 2][lm] = b.z; Bs[lk4 + 3][lm] = b.w;
    __syncthreads();
#pragma unroll
    for (int kk = 0; kk < 8; ++kk) {
      const float4 a0 = *(const float4*)&As[kk][tm0];
      const float4 a1 = *(const float4*)&As[kk][tm0 + 4];
      const float4 b0 = *(const float4*)&Bs[kk][tn0];
      const float4 b1 = *(const float4*)&Bs[kk][tn0 + 4];
      const float am[8] = {a0.x, a0.y, a0.z, a0.w, a1.x, a1.y, a1.z, a1.w};
      const float bn[8] = {b0.x, b0.y, b0.z, b0.w, b1.x, b1.y, b1.z, b1.w};
#pragma unroll
      for (int i = 0; i < 8; ++i)
#pragma unroll
        for (int j = 0; j < 8; ++j)
          acc[i][j] = fmaf(am[i], bn[j], acc[i][j]);
    }
    __syncthreads();
  }

  float bs[8];
#pragma unroll
  for (int j = 0; j < 8; ++j) {
    const int n = n0 + tn0 + j;
    bs[j] = bias1[n] + (bias2 ? bias2[n] : 0.f);
  }
#pragma unroll
  for (int i = 0; i < 8; ++i) {
    const long r = r0 + tm0 + i;
    const float4 v0 = make_float4(acc[i][0] + bs[0], acc[i][1] + bs[1],
                                  acc[i][2] + bs[2], acc[i][3] + bs[3]);
    const float4 v1 = make_float4(acc[i][4] + bs[4], acc[i][5] + bs[5],
                                  acc[i][6] + bs[6], acc[i][7] + bs[7]);
    *(float4*)(C + r * N + n0 + tn0)     = v0;
    *(float4*)(C + r * N + n0 + tn0 + 4) = v1;
  }
}

// ---------------------------------------------------------------------------
// Grid barrier — EXACT round-4 form (hardware-validated correct).
// Fences are mandatory: relaxed agent atomics do NOT give cross-XCD data
// visibility (round-7 failure, absmax 0.196). The acquire fence invalidates
// L1+L2, so everything reread after it must be LDS-resident or cheap.
// ---------------------------------------------------------------------------
__device__ __forceinline__ void grid_barrier(unsigned* cnt, unsigned target)
{
  __syncthreads();   // compiler drains vmcnt before s_barrier -> stores acked
  if (threadIdx.x == 0) {
    __threadfence();  // release: L2 writeback -> coherent point
    __hip_atomic_fetch_add(cnt, 1u, __ATOMIC_ACQ_REL, __HIP_MEMORY_SCOPE_AGENT);
    while (__hip_atomic_load(cnt, __ATOMIC_ACQUIRE, __HIP_MEMORY_SCOPE_AGENT) < target)
      __builtin_amdgcn_s_sleep(1);
    __threadfence();  // acquire: L1/L2 invalidate -> fresh reads
  }
  __syncthreads();
}

// lane-select without runtime array indexing (keeps values in VGPRs)
__device__ __forceinline__ float sel4(float a, float b, float c, float d, int u)
{
  return (u & 2) ? ((u & 1) ? d : c) : ((u & 1) ? b : a);
}

// ---------------------------------------------------------------------------
// FUSED persistent scan v3. Single 256-WG domain; WG owns 4 units (u0=wg*4).
// LDS holds ALL per-unit weights (the round-4 counters showed the barrier's
// L2-invalidate was forcing ~5MB/step of W_in/W_rec/h refetch = the real cost):
//   rows 0..15  W_hh (row = ug*4+gate), rows 16..19 W_in, rows 20..23 W_rec,
//   quarter-padded (quarter q at q*260; bases hit banks {0,4,8,12}).
// Thread (bg,u,ug) = (t>>4, (t>>2)&3, t&3): for 4 batches b0=bg*4..+3 and
// unit u0+ug, partial dots over k-quarter u for {4 gates, fc_in, W_rec}
// (6144 FMA/thread/step, 1B weight per FMA). Combine via shfl_xor(4,8).
// Liquid lags LSTM by one step -> ONE barrier/step. c and liquid state in
// registers (redundant across the 4 u-lanes, identical after combine).
// ---------------------------------------------------------------------------
__global__ __launch_bounds__(256) void fused_scan(
    const float* __restrict__ W_hh, const float* __restrict__ W_in,
    const float* __restrict__ W_rec, const float* __restrict__ gx,
    const float* __restrict__ b_in, const float* __restrict__ b_rec,
    const float* __restrict__ tau,
    float* __restrict__ hA, float* __restrict__ hB,
    float* __restrict__ hLA, float* __restrict__ hLB,
    float* __restrict__ cbuf, float* __restrict__ out,
    unsigned* __restrict__ cnt, int base, int nsteps, int do_epi)
{
  __shared__ float Wl[24][1044];   // ~98KB
  const int wg = blockIdx.x, t = threadIdx.x;
  const int u0 = wg * 4;

  { // stage 24 rows x 1024 floats: row j, thread t loads float4 at t*4
    const int k = t * 4;
    const int dst = (k >> 8) * 260 + (k & 255);
#pragma unroll
    for (int j = 0; j < 24; ++j) {
      const float* src;
      if (j < 16)      src = W_hh  + ((long)(j & 3) * H_ + u0 + (j >> 2)) * H_;
      else if (j < 20) src = W_in  + (long)(u0 + (j - 16)) * H_;
      else             src = W_rec + (long)(u0 + (j - 20)) * H_;
      *(float4*)&Wl[j][dst] = *(const float4*)(src + k);
    }
  }
  __syncthreads();

  const int ug = t & 3;
  const int u  = (t >> 2) & 3;
  const int bg = t >> 4;
  const int unit = u0 + ug;
  const int b0 = bg * 4;

  const float* wg0 = &Wl[ug * 4 + 0][u * 260];   // gate i
  const float* wg1 = &Wl[ug * 4 + 1][u * 260];   // gate f
  const float* wg2 = &Wl[ug * 4 + 2][u * 260];   // gate g
  const float* wg3 = &Wl[ug * 4 + 3][u * 260];   // gate o
  const float* wiq = &Wl[16 + ug][u * 260];      // fc_in row
  const float* wrq = &Wl[20 + ug][u * 260];      // W_rec row

  const float tc   = fminf(fmaxf(tau[unit], 0.1f), 5.0f);
  const float leak = 0.1f / tc;
  const float br   = b_rec[unit];
  const float bi   = b_in[unit];

  float c0 = cbuf[(long)(b0 + 0) * H_ + unit];
  float c1 = cbuf[(long)(b0 + 1) * H_ + unit];
  float c2 = cbuf[(long)(b0 + 2) * H_ + unit];
  float c3 = cbuf[(long)(b0 + 3) * H_ + unit];
  // liquid self-state = state_{base-2}; always in hLB at (even) chunk entry
  float s0 = hLB[(long)(b0 + 0) * H_ + unit];
  float s1 = hLB[(long)(b0 + 1) * H_ + unit];
  float s2 = hLB[(long)(b0 + 2) * H_ + unit];
  float s3 = hLB[(long)(b0 + 3) * H_ + unit];

  for (int ls = 0; ls < nsteps; ++ls) {
    const int s = base + ls;
    const float* hp  = (s & 1) ? hB : hA;    // h_{s-1}
    float*       hn  = (s & 1) ? hA : hB;    // h_s
    const float* hLp = (s & 1) ? hLA : hLB;  // state_{s-2}
    float*       hLn = (s & 1) ? hLB : hLA;  // state_{s-1}

    const float* hq0 = hp  + (long)(b0 + 0) * H_ + u * 256;
    const float* hq1 = hp  + (long)(b0 + 1) * H_ + u * 256;
    const float* hq2 = hp  + (long)(b0 + 2) * H_ + u * 256;
    const float* hq3 = hp  + (long)(b0 + 3) * H_ + u * 256;
    const float* lq0 = hLp + (long)(b0 + 0) * H_ + u * 256;
    const float* lq1 = hLp + (long)(b0 + 1) * H_ + u * 256;
    const float* lq2 = hLp + (long)(b0 + 2) * H_ + u * 256;
    const float* lq3 = hLp + (long)(b0 + 3) * H_ + u * 256;

    float p00 = 0.f, p01 = 0.f, p02 = 0.f, p03 = 0.f;   // gate i, batches 0..3
    float p10 = 0.f, p11 = 0.f, p12 = 0.f, p13 = 0.f;   // gate f
    float p20 = 0.f, p21 = 0.f, p22 = 0.f, p23 = 0.f;   // gate g
    float p30 = 0.f, p31 = 0.f, p32 = 0.f, p33 = 0.f;   // gate o
    float q0 = 0.f, q1 = 0.f, q2 = 0.f, q3 = 0.f;       // fc_in
    float r0 = 0.f, r1 = 0.f, r2 = 0.f, r3 = 0.f;       // liquid rec

#define DOTBB(HQ, LQ, P0, P1, P2, P3, QQ, RR)                                  \
    { const float4 hv = *(const float4*)(HQ + ko);                             \
      const float4 lv = *(const float4*)(LQ + ko);                             \
      P0 = fmaf(hv.x, a0.x, fmaf(hv.y, a0.y, fmaf(hv.z, a0.z, fmaf(hv.w, a0.w, P0)))); \
      P1 = fmaf(hv.x, a1.x, fmaf(hv.y, a1.y, fmaf(hv.z, a1.z, fmaf(hv.w, a1.w, P1)))); \
      P2 = fmaf(hv.x, a2.x, fmaf(hv.y, a2.y, fmaf(hv.z, a2.z, fmaf(hv.w, a2.w, P2)))); \
      P3 = fmaf(hv.x, a3.x, fmaf(hv.y, a3.y, fmaf(hv.z, a3.z, fmaf(hv.w, a3.w, P3)))); \
      QQ = fmaf(hv.x, wiv.x, fmaf(hv.y, wiv.y, fmaf(hv.z, wiv.z, fmaf(hv.w, wiv.w, QQ)))); \
      RR = fmaf(lv.x, wrv.x, fmaf(lv.y, wrv.y, fmaf(lv.z, wrv.z, fmaf(lv.w, wrv.w, RR)))); }

#pragma unroll 2
    for (int k4 = 0; k4 < 64; ++k4) {
      const int ko = k4 * 4;
      const float4 a0  = *(const float4*)(wg0 + ko);
      const float4 a1  = *(const float4*)(wg1 + ko);
      const float4 a2  = *(const float4*)(wg2 + ko);
      const float4 a3  = *(const float4*)(wg3 + ko);
      const float4 wiv = *(const float4*)(wiq + ko);
      const float4 wrv = *(const float4*)(wrq + ko);
      DOTBB(hq0, lq0, p00, p10, p20, p30, q0, r0)
      DOTBB(hq1, lq1, p01, p11, p21, p31, q1, r1)
      DOTBB(hq2, lq2, p02, p12, p22, p32, q2, r2)
      DOTBB(hq3, lq3, p03, p13, p23, p33, q3, r3)
    }
#undef DOTBB

    // combine the 4 k-quarters (u = lane bits 2-3)
#define CMB(X) X += __shfl_xor(X, 4, 64); X += __shfl_xor(X, 8, 64);
    CMB(p00) CMB(p01) CMB(p02) CMB(p03)
    CMB(p10) CMB(p11) CMB(p12) CMB(p13)
    CMB(p20) CMB(p21) CMB(p22) CMB(p23)
    CMB(p30) CMB(p31) CMB(p32) CMB(p33)
    CMB(q0) CMB(q1) CMB(q2) CMB(q3)
    CMB(r0) CMB(r1) CMB(r2) CMB(r3)
#undef CMB

    // ---- LSTM updates (4 batches; redundant across u-lanes) ----
    float hn0, hn1, hn2, hn3;
#define LSTM(bb, PI, PF, PG, PO, CC, HN)                                   \
    { const float* gp = gx + ((long)ls * B_ + (b0 + bb)) * (4 * H_);       \
      const float gi = PI + gp[unit];                                      \
      const float gf = PF + gp[H_ + unit];                                 \
      const float gg = PG + gp[2 * H_ + unit];                             \
      const float go = PO + gp[3 * H_ + unit];                             \
      const float si_ = 1.f / (1.f + __expf(-gi));                         \
      const float sf_ = 1.f / (1.f + __expf(-gf));                         \
      const float so_ = 1.f / (1.f + __expf(-go));                         \
      CC = sf_ * CC + si_ * tanhf(gg);                                     \
      HN = so_ * tanhf(CC); }
    LSTM(0, p00, p10, p20, p30, c0, hn0)
    LSTM(1, p01, p11, p21, p31, c1, hn1)
    LSTM(2, p02, p12, p22, p32, c2, hn2)
    LSTM(3, p03, p13, p23, p33, c3, hn3)
#undef LSTM
    hn[(long)(b0 + u) * H_ + unit] = sel4(hn0, hn1, hn2, hn3, u);

    // ---- liquid update for step s-1 (skip at s==0) ----
    if (s > 0) {
      const float a0_ = tanhf(q0 + bi + r0 + br);
      const float a1_ = tanhf(q1 + bi + r1 + br);
      const float a2_ = tanhf(q2 + bi + r2 + br);
      const float a3_ = tanhf(q3 + bi + r3 + br);
      s0 += leak * (a0_ - s0);
      s1 += leak * (a1_ - s1);
      s2 += leak * (a2_ - s2);
      s3 += leak * (a3_ - s3);
      hLn[(long)(b0 + u) * H_ + unit] = sel4(s0, s1, s2, s3, u);
    }

    grid_barrier(cnt, (unsigned)(s + 1) * 256u);
  }
  cbuf[(long)(b0 + u) * H_ + unit] = sel4(c0, c1, c2, c3, u);

  // ---- epilogue (last chunk): liquid step T-1 -> out ----
  if (do_epi) {
    const int sl = base + nsteps - 1;           // = T_-1 (odd)
    const float* hp  = (sl & 1) ? hA : hB;      // h_{T-1}
    const float* hLp = (sl & 1) ? hLB : hLA;    // state_{T-2}
    const float* hq0 = hp  + (long)(b0 + 0) * H_ + u * 256;
    const float* hq1 = hp  + (long)(b0 + 1) * H_ + u * 256;
    const float* hq2 = hp  + (long)(b0 + 2) * H_ + u * 256;
    const float* hq3 = hp  + (long)(b0 + 3) * H_ + u * 256;
    const float* lq0 = hLp + (long)(b0 + 0) * H_ + u * 256;
    const float* lq1 = hLp + (long)(b0 + 1) * H_ + u * 256;
    const float* lq2 = hLp + (long)(b0 + 2) * H_ + u * 256;
    const float* lq3 = hLp + (long)(b0 + 3) * H_ + u * 256;
    float q0 = 0.f, q1 = 0.f, q2 = 0.f, q3 = 0.f;
    float r0 = 0.f, r1 = 0.f, r2 = 0.f, r3 = 0.f;
#define EDOT(HQ, LQ, QQ, RR)                                                   \
    { const float4 hv = *(const float4*)(HQ + ko);                             \
      const float4 lv = *(const float4*)(LQ + ko);                             \
      QQ = fmaf(hv.x, wiv.x, fmaf(hv.y, wiv.y, fmaf(hv.z, wiv.z, fmaf(hv.w, wiv.w, QQ)))); \
      RR = fmaf(lv.x, wrv.x, fmaf(lv.y, wrv.y, fmaf(lv.z, wrv.z, fmaf(lv.w, wrv.w, RR)))); }
#pragma unroll 4
    for (int k4 = 0; k4 < 64; ++k4) {
      const int ko = k4 * 4;
      const float4 wiv = *(const float4*)(wiq + ko);
      const float4 wrv = *(const float4*)(wrq + ko);
      EDOT(hq0, lq0, q0, r0)
      EDOT(hq1, lq1, q1, r1)
      EDOT(hq2, lq2, q2, r2)
      EDOT(hq3, lq3, q3, r3)
    }
#undef EDOT
#define CMB(X) X += __shfl_xor(X, 4, 64); X += __shfl_xor(X, 8, 64);
    CMB(q0) CMB(q1) CMB(q2) CMB(q3)
    CMB(r0) CMB(r1) CMB(r2) CMB(r3)
#undef CMB
    const float a0_ = tanhf(q0 + bi + r0 + br);
    const float a1_ = tanhf(q1 + bi + r1 + br);
    const float a2_ = tanhf(q2 + bi + r2 + br);
    const float a3_ = tanhf(q3 + bi + r3 + br);
    const float o0 = s0 + leak * (a0_ - s0);
    const float o1 = s1 + leak * (a1_ - s1);
    const float o2 = s2 + leak * (a2_ - s2);
    const float o3 = s3 + leak * (a3_ - s3);
    out[(long)(b0 + u) * H_ + unit] = sel4(o0, o1, o2, o3, u);
  }
}

// ---------------------------------------------------------------------------
extern "C" void kernel_launch(void* const* d_in, const int* in_sizes, int n_in,
                              void* d_out, int out_size, void* d_ws, size_t ws_size,
                              hipStream_t stream)
{
  (void)in_sizes; (void)n_in; (void)out_size;
  const float* x     = (const float*)d_in[0];
  const float* W_ih  = (const float*)d_in[1];
  const float* W_hh  = (const float*)d_in[2];
  const float* b_ih  = (const float*)d_in[3];
  const float* b_hh  = (const float*)d_in[4];
  const float* W_in  = (const float*)d_in[5];
  const float* b_in  = (const float*)d_in[6];
  const float* W_rec = (const float*)d_in[7];
  const float* b_rec = (const float*)d_in[8];
  const float* tau   = (const float*)d_in[9];

  const size_t HB   = (size_t)B_ * H_ * sizeof(float);   // 256 KiB
  const size_t TAIL = 5 * HB + 1024;                     // cbuf,hA,hB,hLA,hLB,cnt

  int Tc = T_;
  while (Tc > 2) {
    const size_t need = (size_t)Tc * B_ * 4 * H_ * 4 + TAIL;
    if (need <= ws_size) break;
    Tc >>= 1;
  }

  char* ws = (char*)d_ws;
  const size_t GXB = (size_t)Tc * B_ * 4 * H_ * sizeof(float);
  float* gx   = (float*)ws;                    // [Tc][B][4H]
  char*  tail = ws + GXB;
  float* cbuf = (float*)(tail);
  float* hA   = (float*)(tail + 1 * HB);
  float* hB   = (float*)(tail + 2 * HB);
  float* hLA  = (float*)(tail + 3 * HB);
  float* hLB  = (float*)(tail + 4 * HB);
  unsigned* cnt = (unsigned*)(tail + 5 * HB);
  float* outp = (float*)d_out;

  hipMemsetAsync(tail, 0, TAIL, stream);

  const int nch = T_ / Tc;
  for (int k = 0; k < nch; ++k) {
    int t0 = k * Tc;
    int ns = Tc;
    int epi = (k == nch - 1) ? 1 : 0;

    gemm_bt_bias<<<dim3(4 * H_ / 128, Tc * B_ / 128), 256, 0, stream>>>(
        x + (long)t0 * I_, W_ih, b_ih, b_hh, gx, 4 * H_, I_,
        (long)T_ * I_, (long)I_);

    {
      void* args[] = {(void*)&W_hh, (void*)&W_in, (void*)&W_rec, (void*)&gx,
                      (void*)&b_in, (void*)&b_rec, (void*)&tau,
                      (void*)&hA, (void*)&hB, (void*)&hLA, (void*)&hLB,
                      (void*)&cbuf, (void*)&outp, (void*)&cnt,
                      (void*)&t0, (void*)&ns, (void*)&epi};
      hipLaunchCooperativeKernel((void*)fused_scan, dim3(256), dim3(256),
                                 args, 0, stream);
    }
  }
}